// Round 8
// baseline (458.696 us; speedup 1.0000x reference)
//
#include <hip/hip_runtime.h>

typedef __attribute__((ext_vector_type(4))) float f32x4;
typedef __attribute__((ext_vector_type(8))) short short8;
typedef __attribute__((ext_vector_type(2))) unsigned short ushort2v;
typedef __attribute__((ext_vector_type(4))) unsigned short ushort4v;

#define D_MODEL 1024
#define NH 16
#define DK 64
#define BSZ 4
#define SSZ 2048
#define M_TOT (BSZ * SSZ)   // 8192

__device__ __forceinline__ unsigned short f2bf(float f) {
  unsigned int u = __float_as_uint(f);
  u = (u + 0x7FFFu + ((u >> 16) & 1u)) >> 16;   // RTNE
  return (unsigned short)u;
}
__device__ __forceinline__ float bf2f(unsigned short h) {
  return __uint_as_float(((unsigned int)h) << 16);
}
__device__ __forceinline__ unsigned int pk_bf16(float lo, float hi) {
  unsigned int r;
  asm("v_cvt_pk_bf16_f32 %0, %1, %2" : "=v"(r) : "v"(lo), "v"(hi));
  return r;
}
__device__ __forceinline__ float fast_exp2(float x) {   // 2^x via v_exp_f32
  float r;
  asm("v_exp_f32 %0, %1" : "=v"(r) : "v"(x));
  return r;
}

// ---------------------------------------------------------------- convert
__global__ void convert_kernel(const float* __restrict__ x,
                               const float* __restrict__ Qw,
                               const float* __restrict__ Kw,
                               const float* __restrict__ Vw,
                               const float* __restrict__ Ow,
                               unsigned short* __restrict__ xb,
                               unsigned short* __restrict__ wqkv,
                               unsigned short* __restrict__ owb) {
  const int NX = M_TOT * D_MODEL;        // 8388608
  const int NO = D_MODEL * D_MODEL;      // 1048576
  const int NW = 3 * NO;
  int idx = (blockIdx.x * blockDim.x + threadIdx.x) * 4;
  const float* src;
  unsigned short* dst;
  if (idx < NX) {
    src = x + idx; dst = xb + idx;
  } else if (idx < NX + NW) {
    int j = idx - NX;
    dst = wqkv + j;
    if (j < NO)            src = Qw + j;
    else if (j < 2 * NO)   src = Kw + (j - NO);
    else                   src = Vw + (j - 2 * NO);
  } else {
    int j = idx - NX - NW;
    src = Ow + j; dst = owb + j;
  }
  float4 v = *(const float4*)src;
  ushort4v o;
  o.x = f2bf(v.x); o.y = f2bf(v.y); o.z = f2bf(v.z); o.w = f2bf(v.w);
  *(ushort4v*)dst = o;
}

// ---------------------------------------------------------------- GEMM (NT, bf16, 128x128 tile, BK=32)
template <int MODE>
__global__ __launch_bounds__(256) void gemm_kernel(const unsigned short* __restrict__ A,
                                                   const unsigned short* __restrict__ Bm,
                                                   unsigned short* __restrict__ oQ,
                                                   unsigned short* __restrict__ oK,
                                                   unsigned short* __restrict__ oV,
                                                   float* __restrict__ oF) {
  __shared__ unsigned short As[128 * 32];
  __shared__ unsigned short Bs[128 * 32];
  const int t = threadIdx.x;
  const int lane = t & 63, wave = t >> 6;
  const int l15 = lane & 15, g = lane >> 4;
  const int wr = wave >> 1, wc = wave & 1;
  const int brow = blockIdx.x * 128;
  const int bcol = blockIdx.y * 128;
  const int rA = t >> 2, c8 = (t & 3) * 8;

  f32x4 acc[4][4] = {};

  for (int k0 = 0; k0 < 1024; k0 += 32) {
    __syncthreads();
#pragma unroll
    for (int i = 0; i < 2; ++i) {
      const unsigned short* sa = A + (size_t)(brow + rA + 64 * i) * 1024 + k0 + c8;
      __builtin_amdgcn_global_load_lds((const __attribute__((address_space(1))) void*)sa,
                                       (__attribute__((address_space(3))) void*)(&As[(t + 256 * i) * 8]),
                                       16, 0, 0);
      const unsigned short* sb = Bm + (size_t)(bcol + rA + 64 * i) * 1024 + k0 + c8;
      __builtin_amdgcn_global_load_lds((const __attribute__((address_space(1))) void*)sb,
                                       (__attribute__((address_space(3))) void*)(&Bs[(t + 256 * i) * 8]),
                                       16, 0, 0);
    }
    __syncthreads();
    short8 a[4], b[4];
#pragma unroll
    for (int m = 0; m < 4; ++m)
      a[m] = *(const short8*)(&As[(wr * 64 + m * 16 + l15) * 32 + g * 8]);
#pragma unroll
    for (int n = 0; n < 4; ++n)
      b[n] = *(const short8*)(&Bs[(wc * 64 + n * 16 + l15) * 32 + g * 8]);
#pragma unroll
    for (int m = 0; m < 4; ++m)
#pragma unroll
      for (int n = 0; n < 4; ++n)
        acc[m][n] = __builtin_amdgcn_mfma_f32_16x16x32_bf16(a[m], b[n], acc[m][n], 0, 0, 0);
  }

  const int mbase = brow + wr * 64;
  const int nbase = bcol + wc * 64;
  if (MODE == 0) {
    const int which = bcol >> 10;   // uniform per block (128 | 1024)
#pragma unroll
    for (int m = 0; m < 4; ++m) {
#pragma unroll
      for (int n = 0; n < 4; ++n) {
#pragma unroll
        for (int r = 0; r < 4; ++r) {
          int mrow = mbase + m * 16 + g * 4 + r;
          int ncol = nbase + n * 16 + l15;
          int b = mrow >> 11, s = mrow & 2047;
          int rem = ncol & 1023;
          int h = rem >> 6, d = rem & 63;
          int bh = b * NH + h;
          unsigned short val = f2bf(acc[m][n][r]);
          if (which == 0)      oQ[((size_t)bh * SSZ + s) * DK + d] = val;
          else if (which == 1) oK[((size_t)bh * SSZ + s) * DK + d] = val;
          else                 oV[((size_t)bh * DK + d) * SSZ + s] = val;
        }
      }
    }
  } else {
#pragma unroll
    for (int m = 0; m < 4; ++m) {
#pragma unroll
      for (int n = 0; n < 4; ++n) {
#pragma unroll
        for (int r = 0; r < 4; ++r) {
          int mrow = mbase + m * 16 + g * 4 + r;
          int ncol = nbase + n * 16 + l15;
          oF[(size_t)mrow * D_MODEL + ncol] = acc[m][n][r];
        }
      }
    }
  }
}

// ---------------------------------------------------------------- RoPE (in-place on bf16 Q/K)
// Q gets 0.125 * log2(e) folded in: scores come out in log2 domain -> exp2.
__global__ void rope_kernel(unsigned short* __restrict__ Qb,
                            unsigned short* __restrict__ Kb,
                            const int* __restrict__ pos) {
  int idx = blockIdx.x * blockDim.x + threadIdx.x;  // BH*S*32 threads
  int i = idx & 31;
  int s = (idx >> 5) & (SSZ - 1);
  int bh = idx >> 16;
  int b = bh >> 4;
  float p = (float)pos[b * SSZ + s];
  const float KC = 0.28782313662425572f;  // ln(10000)/32
  float invf = expf(-KC * (float)i);
  float ang = p * invf;
  float sn, cs;
  sincosf(ang, &sn, &cs);
  size_t off = ((size_t)bh * SSZ + s) * DK + 2 * i;

  const float QS = 0.18033688011112042f;  // 0.125 * log2(e)
  ushort2v q = *(ushort2v*)(Qb + off);
  float qe = bf2f(q.x), qo = bf2f(q.y);
  float re = (qe * cs - qo * sn) * QS;
  float ro = (qe * sn + qo * cs) * QS;
  q.x = f2bf(re); q.y = f2bf(ro);
  *(ushort2v*)(Qb + off) = q;

  ushort2v k = *(ushort2v*)(Kb + off);
  float ke = bf2f(k.x), ko = bf2f(k.y);
  float rke = ke * cs - ko * sn;
  float rko = ke * sn + ko * cs;
  k.x = f2bf(rke); k.y = f2bf(rko);
  *(ushort2v*)(Kb + off) = k;
}

// ---------------------------------------------------------------- flash attention v5
// (swapped QK^T, XCD-swizzle, T13 defer-max, deferred cross-lane sum, exp2,
//  single-K-buffer prefetch-after-use)
__global__ __launch_bounds__(256) void attn_kernel(const unsigned short* __restrict__ Qb,
                                                   const unsigned short* __restrict__ Kb,
                                                   const unsigned short* __restrict__ Vt,
                                                   unsigned short* __restrict__ Ob) {
  __shared__ unsigned short PL[4 * 1024];    // per-wave 16q x 64k bf16 (2KB each)
  const int id = blockIdx.x;
  const int xcd = id & 7, j = id >> 3;
  const int bh = 8 * xcd + (j & 7);
  const int bx = j >> 3;                     // 0..15
  const int lane = threadIdx.x & 63, wave = threadIdx.x >> 6;
  const int l15 = lane & 15, g = lane >> 4;
  const size_t bhS = (size_t)bh * SSZ;
  char* plb = (char*)PL + wave * 2048;
  const int swz = (l15 & 7) << 4;
  const int b = bh >> 4, h = bh & 15;

#pragma unroll 1
  for (int half = 0; half < 2; ++half) {
    const int qt = half ? (31 - bx) : bx;
    const int qw0 = qt * 64 + wave * 16;
    short8 qf[2];
#pragma unroll
    for (int ds = 0; ds < 2; ++ds)
      qf[ds] = *(const short8*)(Qb + (bhS + qw0 + l15) * DK + ds * 32 + g * 8);

    f32x4 acc[4] = {};
    float mrun = -3.0e38f, lrun = 0.f;
    const int njt = qt + 1;

    short8 ka[4][2];
    auto loadK = [&](int j0) {
#pragma unroll
      for (int c = 0; c < 4; ++c)
#pragma unroll
        for (int ds = 0; ds < 2; ++ds)
          ka[c][ds] = *(const short8*)(Kb + (bhS + j0 + c * 16 + l15) * DK + ds * 32 + g * 8);
    };

    loadK(0);
#pragma unroll 1
    for (int jt = 0; jt < njt; ++jt) {
      const int j0 = jt * 64;
      const bool last = (jt == njt - 1);
      // V loads for THIS tile issue first: QK + softmax covers their latency.
      short8 vf[4][2];
#pragma unroll
      for (int n = 0; n < 4; ++n)
#pragma unroll
        for (int d2 = 0; d2 < 2; ++d2)
          vf[n][d2] = *(const short8*)(Vt + ((size_t)bh * DK + n * 16 + l15) * SSZ + j0 + d2 * 32 + g * 8);

      // QK^T swapped: st[c][r] = S[k = c*16 + g*4 + r][q = l15], log2 domain
      f32x4 st[4] = {};
#pragma unroll
      for (int c = 0; c < 4; ++c)
#pragma unroll
        for (int ds = 0; ds < 2; ++ds)
          st[c] = __builtin_amdgcn_mfma_f32_16x16x32_bf16(ka[c][ds], qf[ds], st[c], 0, 0, 0);

      // prefetch next tile's K into the SAME registers (after last use):
      // issue->use distance = softmax + PV (~500cy)
      if (!last) loadK(j0 + 64);

      if (last) {   // causal mask, only last tile
        const int qrow = qw0 + l15;
#pragma unroll
        for (int c = 0; c < 4; ++c) {
          const int kbse = j0 + c * 16 + g * 4;
#pragma unroll
          for (int r = 0; r < 4; ++r)
            if (kbse + r > qrow) st[c][r] = -3.0e38f;
        }
      }

      // in-lane tree max (no cross-lane)
      float mc[4];
#pragma unroll
      for (int c = 0; c < 4; ++c)
        mc[c] = fmaxf(fmaxf(st[c][0], st[c][1]), fmaxf(st[c][2], st[c][3]));
      float pmax = fmaxf(fmaxf(mc[0], mc[1]), fmaxf(mc[2], mc[3]));

      // T13 defer-max: only when some lane's max grew past mrun+8 do the
      // cross-lane reduce + uniform rescale. mrun stays wave-uniform per q.
      if (!__all(pmax <= mrun + 8.0f)) {
        float mx = fmaxf(pmax, __shfl_xor(pmax, 16));
        mx = fmaxf(mx, __shfl_xor(mx, 32));
        const float mnew = fmaxf(mrun, mx);
        const float corr = fast_exp2(mrun - mnew);
        mrun = mnew;
        lrun *= corr;
#pragma unroll
        for (int n = 0; n < 4; ++n)
#pragma unroll
          for (int r = 0; r < 4; ++r) acc[n][r] *= corr;
      }

      // exp2 + per-lane partial sum (cross-lane sum deferred to epilogue)
      float sc_[4];
#pragma unroll
      for (int c = 0; c < 4; ++c) {
#pragma unroll
        for (int r = 0; r < 4; ++r)
          st[c][r] = fast_exp2(st[c][r] - mrun);
        sc_[c] = (st[c][0] + st[c][1]) + (st[c][2] + st[c][3]);
      }
      lrun += (sc_[0] + sc_[1]) + (sc_[2] + sc_[3]);

      // pack P^T -> per-wave LDS (XOR-swizzled rows)
#pragma unroll
      for (int c = 0; c < 4; ++c) {
        uint2 ww;
        ww.x = pk_bf16(st[c][0], st[c][1]);
        ww.y = pk_bf16(st[c][2], st[c][3]);
        *(uint2*)(plb + ((l15 * 128 + c * 32 + g * 8) ^ swz)) = ww;
      }
      asm volatile("s_waitcnt lgkmcnt(0)" ::: "memory");
      __builtin_amdgcn_sched_barrier(0);
      short8 pf[2];
#pragma unroll
      for (int d2 = 0; d2 < 2; ++d2)
        pf[d2] = *(const short8*)(plb + ((l15 * 128 + d2 * 64 + g * 16) ^ swz));
      // PV: out^T[d][q]
#pragma unroll
      for (int n = 0; n < 4; ++n)
#pragma unroll
        for (int d2 = 0; d2 < 2; ++d2)
          acc[n] = __builtin_amdgcn_mfma_f32_16x16x32_bf16(vf[n][d2], pf[d2], acc[n], 0, 0, 0);
    }

    // deferred cross-lane sum: once per half
    lrun += __shfl_xor(lrun, 16);
    lrun += __shfl_xor(lrun, 32);
    const float inv = 1.f / lrun;
    const size_t base = ((size_t)b * SSZ + qw0 + l15) * D_MODEL + h * DK;
#pragma unroll
    for (int n = 0; n < 4; ++n) {
      uint2 ww;
      ww.x = pk_bf16(acc[n][0] * inv, acc[n][1] * inv);
      ww.y = pk_bf16(acc[n][2] * inv, acc[n][3] * inv);
      *(uint2*)((char*)(Ob + base + n * 16 + g * 4)) = ww;
    }
  }
}

// ---------------------------------------------------------------- launch
extern "C" void kernel_launch(void* const* d_in, const int* in_sizes, int n_in,
                              void* d_out, int out_size, void* d_ws, size_t ws_size,
                              hipStream_t stream) {
  const float* x  = (const float*)d_in[0];
  const int* pos  = (const int*)d_in[1];
  const float* Qw = (const float*)d_in[2];
  const float* Kw = (const float*)d_in[3];
  const float* Vw = (const float*)d_in[4];
  const float* Ow = (const float*)d_in[5];
  float* out = (float*)d_out;

  unsigned short* xb   = (unsigned short*)d_ws;              // 8192*1024
  unsigned short* wqkv = xb + (size_t)M_TOT * D_MODEL;       // 3072*1024
  unsigned short* owb  = wqkv + (size_t)3 * D_MODEL * D_MODEL;
  unsigned short* Qb   = owb + (size_t)D_MODEL * D_MODEL;    // [64][2048][64]
  unsigned short* Kb   = Qb + (size_t)64 * SSZ * DK;
  unsigned short* Vt   = Kb + (size_t)64 * SSZ * DK;         // [64][64][2048]
  unsigned short* Ob   = Vt + (size_t)64 * SSZ * DK;         // [8192][1024]

  // 1. convert inputs to bf16
  {
    int total = M_TOT * D_MODEL + 4 * D_MODEL * D_MODEL;     // 12582912
    convert_kernel<<<total / 4 / 256, 256, 0, stream>>>(x, Qw, Kw, Vw, Ow, xb, wqkv, owb);
  }
  // 2. QKV projection (N=3072)
  gemm_kernel<0><<<dim3(M_TOT / 128, 3072 / 128), 256, 0, stream>>>(xb, wqkv, Qb, Kb, Vt, nullptr);
  // 3. RoPE in place on Q,K (Q gets 0.125*log2e folded in)
  rope_kernel<<<(64 * SSZ * 32) / 256, 256, 0, stream>>>(Qb, Kb, pos);
  // 4. causal flash attention (XCD-swizzled 1-D grid)
  attn_kernel<<<1024, 256, 0, stream>>>(Qb, Kb, Vt, Ob);
  // 5. output projection -> fp32 d_out
  gemm_kernel<1><<<dim3(M_TOT / 128, D_MODEL / 128), 256, 0, stream>>>(Ob, owb, nullptr, nullptr, nullptr, out);
}

// Round 10
// 280.830 us; speedup vs baseline: 1.6334x; 1.6334x over previous
//
#include <hip/hip_runtime.h>

typedef __attribute__((ext_vector_type(4))) float f32x4;
typedef __attribute__((ext_vector_type(8))) short short8;
typedef __attribute__((ext_vector_type(2))) unsigned short ushort2v;
typedef __attribute__((ext_vector_type(4))) unsigned short ushort4v;

#define D_MODEL 1024
#define NH 16
#define DK 64
#define BSZ 4
#define SSZ 2048
#define M_TOT (BSZ * SSZ)   // 8192

__device__ __forceinline__ unsigned short f2bf(float f) {
  unsigned int u = __float_as_uint(f);
  u = (u + 0x7FFFu + ((u >> 16) & 1u)) >> 16;   // RTNE
  return (unsigned short)u;
}
__device__ __forceinline__ float bf2f(unsigned short h) {
  return __uint_as_float(((unsigned int)h) << 16);
}
__device__ __forceinline__ unsigned int pk_bf16(float lo, float hi) {
  unsigned int r;
  asm("v_cvt_pk_bf16_f32 %0, %1, %2" : "=v"(r) : "v"(lo), "v"(hi));
  return r;
}
__device__ __forceinline__ float fast_exp2(float x) {   // 2^x via v_exp_f32
  float r;
  asm("v_exp_f32 %0, %1" : "=v"(r) : "v"(x));
  return r;
}

// ---------------------------------------------------------------- convert
__global__ void convert_kernel(const float* __restrict__ x,
                               const float* __restrict__ Qw,
                               const float* __restrict__ Kw,
                               const float* __restrict__ Vw,
                               const float* __restrict__ Ow,
                               unsigned short* __restrict__ xb,
                               unsigned short* __restrict__ wqkv,
                               unsigned short* __restrict__ owb) {
  const int NX = M_TOT * D_MODEL;        // 8388608
  const int NO = D_MODEL * D_MODEL;      // 1048576
  const int NW = 3 * NO;
  int idx = (blockIdx.x * blockDim.x + threadIdx.x) * 4;
  const float* src;
  unsigned short* dst;
  if (idx < NX) {
    src = x + idx; dst = xb + idx;
  } else if (idx < NX + NW) {
    int j = idx - NX;
    dst = wqkv + j;
    if (j < NO)            src = Qw + j;
    else if (j < 2 * NO)   src = Kw + (j - NO);
    else                   src = Vw + (j - 2 * NO);
  } else {
    int j = idx - NX - NW;
    src = Ow + j; dst = owb + j;
  }
  float4 v = *(const float4*)src;
  ushort4v o;
  o.x = f2bf(v.x); o.y = f2bf(v.y); o.z = f2bf(v.z); o.w = f2bf(v.w);
  *(ushort4v*)dst = o;
}

// ---------------------------------------------------------------- GEMM (NT, bf16, 128x128 tile, BK=32)
template <int MODE>
__global__ __launch_bounds__(256) void gemm_kernel(const unsigned short* __restrict__ A,
                                                   const unsigned short* __restrict__ Bm,
                                                   unsigned short* __restrict__ oQ,
                                                   unsigned short* __restrict__ oK,
                                                   unsigned short* __restrict__ oV,
                                                   float* __restrict__ oF) {
  __shared__ unsigned short As[128 * 32];
  __shared__ unsigned short Bs[128 * 32];
  const int t = threadIdx.x;
  const int lane = t & 63, wave = t >> 6;
  const int l15 = lane & 15, g = lane >> 4;
  const int wr = wave >> 1, wc = wave & 1;
  const int brow = blockIdx.x * 128;
  const int bcol = blockIdx.y * 128;
  const int rA = t >> 2, c8 = (t & 3) * 8;

  f32x4 acc[4][4] = {};

  for (int k0 = 0; k0 < 1024; k0 += 32) {
    __syncthreads();
#pragma unroll
    for (int i = 0; i < 2; ++i) {
      const unsigned short* sa = A + (size_t)(brow + rA + 64 * i) * 1024 + k0 + c8;
      __builtin_amdgcn_global_load_lds((const __attribute__((address_space(1))) void*)sa,
                                       (__attribute__((address_space(3))) void*)(&As[(t + 256 * i) * 8]),
                                       16, 0, 0);
      const unsigned short* sb = Bm + (size_t)(bcol + rA + 64 * i) * 1024 + k0 + c8;
      __builtin_amdgcn_global_load_lds((const __attribute__((address_space(1))) void*)sb,
                                       (__attribute__((address_space(3))) void*)(&Bs[(t + 256 * i) * 8]),
                                       16, 0, 0);
    }
    __syncthreads();
    short8 a[4], b[4];
#pragma unroll
    for (int m = 0; m < 4; ++m)
      a[m] = *(const short8*)(&As[(wr * 64 + m * 16 + l15) * 32 + g * 8]);
#pragma unroll
    for (int n = 0; n < 4; ++n)
      b[n] = *(const short8*)(&Bs[(wc * 64 + n * 16 + l15) * 32 + g * 8]);
#pragma unroll
    for (int m = 0; m < 4; ++m)
#pragma unroll
      for (int n = 0; n < 4; ++n)
        acc[m][n] = __builtin_amdgcn_mfma_f32_16x16x32_bf16(a[m], b[n], acc[m][n], 0, 0, 0);
  }

  const int mbase = brow + wr * 64;
  const int nbase = bcol + wc * 64;
  if (MODE == 0) {
    const int which = bcol >> 10;   // uniform per block (128 | 1024)
#pragma unroll
    for (int m = 0; m < 4; ++m) {
#pragma unroll
      for (int n = 0; n < 4; ++n) {
#pragma unroll
        for (int r = 0; r < 4; ++r) {
          int mrow = mbase + m * 16 + g * 4 + r;
          int ncol = nbase + n * 16 + l15;
          int b = mrow >> 11, s = mrow & 2047;
          int rem = ncol & 1023;
          int h = rem >> 6, d = rem & 63;
          int bh = b * NH + h;
          unsigned short val = f2bf(acc[m][n][r]);
          if (which == 0)      oQ[((size_t)bh * SSZ + s) * DK + d] = val;
          else if (which == 1) oK[((size_t)bh * SSZ + s) * DK + d] = val;
          else                 oV[((size_t)bh * DK + d) * SSZ + s] = val;
        }
      }
    }
  } else {
#pragma unroll
    for (int m = 0; m < 4; ++m) {
#pragma unroll
      for (int n = 0; n < 4; ++n) {
#pragma unroll
        for (int r = 0; r < 4; ++r) {
          int mrow = mbase + m * 16 + g * 4 + r;
          int ncol = nbase + n * 16 + l15;
          oF[(size_t)mrow * D_MODEL + ncol] = acc[m][n][r];
        }
      }
    }
  }
}

// ---------------------------------------------------------------- RoPE (in-place on bf16 Q/K)
// Q gets 0.125 * log2(e) folded in: scores come out in log2 domain -> exp2.
__global__ void rope_kernel(unsigned short* __restrict__ Qb,
                            unsigned short* __restrict__ Kb,
                            const int* __restrict__ pos) {
  int idx = blockIdx.x * blockDim.x + threadIdx.x;  // BH*S*32 threads
  int i = idx & 31;
  int s = (idx >> 5) & (SSZ - 1);
  int bh = idx >> 16;
  int b = bh >> 4;
  float p = (float)pos[b * SSZ + s];
  const float KC = 0.28782313662425572f;  // ln(10000)/32
  float invf = expf(-KC * (float)i);
  float ang = p * invf;
  float sn, cs;
  sincosf(ang, &sn, &cs);
  size_t off = ((size_t)bh * SSZ + s) * DK + 2 * i;

  const float QS = 0.18033688011112042f;  // 0.125 * log2(e)
  ushort2v q = *(ushort2v*)(Qb + off);
  float qe = bf2f(q.x), qo = bf2f(q.y);
  float re = (qe * cs - qo * sn) * QS;
  float ro = (qe * sn + qo * cs) * QS;
  q.x = f2bf(re); q.y = f2bf(ro);
  *(ushort2v*)(Qb + off) = q;

  ushort2v k = *(ushort2v*)(Kb + off);
  float ke = bf2f(k.x), ko = bf2f(k.y);
  float rke = ke * cs - ko * sn;
  float rko = ke * sn + ko * cs;
  k.x = f2bf(rke); k.y = f2bf(rko);
  *(ushort2v*)(Kb + off) = k;
}

// ---------------------------------------------------------------- flash attention v6.1
// Block-cooperative LDS staging (2-phase double-buffer). 8 waves x 16 q rows
// = 128 q/block; KV tile 64 staged ONCE per block via coalesced
// global_load_lds with both-sides XOR swizzle. v6.1 fixes the causal-mask
// trigger: mask needed iff j0+63 > qw0 (v6's `j0+48 > qw0` skipped the
// j0 == qw0-48 tile for waves 3/7 -> future-key leak, absmax 0.41).
__global__ __launch_bounds__(512) void attn_kernel(const unsigned short* __restrict__ Qb,
                                                   const unsigned short* __restrict__ Kb,
                                                   const unsigned short* __restrict__ Vt,
                                                   unsigned short* __restrict__ Ob) {
  __shared__ unsigned short KS[2][4096];   // 2 x 64 rows x 64 bf16 (8KB each)
  __shared__ unsigned short VS[2][4096];
  __shared__ unsigned short PL[8 * 1024];  // per-wave 16q x 64k bf16 (2KB each)
  const int id = blockIdx.x;
  const int xcd = id & 7, j = id >> 3;     // 512 blocks = 8 xcd x 8 bh x 8 bx
  const int bh = 8 * xcd + (j & 7);
  const int bx = j >> 3;                   // 0..7
  const int t = threadIdx.x;
  const int lane = t & 63, wave = t >> 6;
  const int l15 = lane & 15, g = lane >> 4;
  const size_t bhS = (size_t)bh * SSZ;
  char* plb = (char*)PL + wave * 2048;
  const int swz = (l15 & 7) << 4;
  const int b = bh >> 4, h = bh & 15;

  // staging geometry: thread t stages 16B; row r = t>>3 (of 64), seg s = t&7
  // (of 8 x 16B per 128B row). LDS linear dest t*16; global source seg
  // pre-swizzled s ^ (r&7) so swizzled reads recover original data.
  const int sr = t >> 3, ss = (t & 7) ^ (sr & 7);
  auto stage = [&](int bb, int j0) {
    const unsigned short* ks = Kb + (bhS + j0 + sr) * DK + ss * 8;
    __builtin_amdgcn_global_load_lds((const __attribute__((address_space(1))) void*)ks,
                                     (__attribute__((address_space(3))) void*)(&KS[bb][t * 8]),
                                     16, 0, 0);
    const unsigned short* vs = Vt + ((size_t)bh * DK + sr) * SSZ + j0 + ss * 8;
    __builtin_amdgcn_global_load_lds((const __attribute__((address_space(1))) void*)vs,
                                     (__attribute__((address_space(3))) void*)(&VS[bb][t * 8]),
                                     16, 0, 0);
  };

#pragma unroll 1
  for (int half = 0; half < 2; ++half) {
    const int qt = half ? (15 - bx) : bx;          // 128-row q tile, 0..15
    const int qw0 = qt * 128 + wave * 16;
    short8 qf[2];
#pragma unroll
    for (int ds = 0; ds < 2; ++ds)
      qf[ds] = *(const short8*)(Qb + (bhS + qw0 + l15) * DK + ds * 32 + g * 8);

    f32x4 acc[4] = {};
    float mrun = -3.0e38f, lrun = 0.f;
    const int njt = 2 * (qt + 1);                  // 64-KV tiles (block-uniform)

    int cur = 0;
    stage(0, 0);
    __syncthreads();

#pragma unroll 1
    for (int jt = 0; jt < njt; ++jt) {
      const int j0 = jt * 64;
      if (jt + 1 < njt) stage(cur ^ 1, j0 + 64);   // prefetch next tile

      // K fragments from LDS (swizzled, conflict-free)
      const unsigned short* Kc = KS[cur];
      short8 kf[4][2];
#pragma unroll
      for (int c = 0; c < 4; ++c)
#pragma unroll
        for (int ds = 0; ds < 2; ++ds)
          kf[c][ds] = *(const short8*)(Kc + (c * 16 + l15) * 64 + (((ds * 4 + g) ^ (l15 & 7)) * 8));

      // QK^T swapped: st[c][r] = S[k = c*16 + g*4 + r][q = l15], log2 domain
      f32x4 st[4] = {};
#pragma unroll
      for (int c = 0; c < 4; ++c)
#pragma unroll
        for (int ds = 0; ds < 2; ++ds)
          st[c] = __builtin_amdgcn_mfma_f32_16x16x32_bf16(kf[c][ds], qf[ds], st[c], 0, 0, 0);

      if (j0 + 64 > qw0) {   // mask needed iff tile max k (j0+63) > min qrow (qw0)
        const int qrow = qw0 + l15;
#pragma unroll
        for (int c = 0; c < 4; ++c) {
          const int kbse = j0 + c * 16 + g * 4;
#pragma unroll
          for (int r = 0; r < 4; ++r)
            if (kbse + r > qrow) st[c][r] = -3.0e38f;
        }
      }

      // in-lane tree max (no cross-lane)
      float mc[4];
#pragma unroll
      for (int c = 0; c < 4; ++c)
        mc[c] = fmaxf(fmaxf(st[c][0], st[c][1]), fmaxf(st[c][2], st[c][3]));
      float pmax = fmaxf(fmaxf(mc[0], mc[1]), fmaxf(mc[2], mc[3]));

      // T13 defer-max: cross-lane reduce + rescale only on max growth >8
      if (!__all(pmax <= mrun + 8.0f)) {
        float mx = fmaxf(pmax, __shfl_xor(pmax, 16));
        mx = fmaxf(mx, __shfl_xor(mx, 32));
        const float mnew = fmaxf(mrun, mx);
        const float corr = fast_exp2(mrun - mnew);
        mrun = mnew;
        lrun *= corr;
#pragma unroll
        for (int n = 0; n < 4; ++n)
#pragma unroll
          for (int r = 0; r < 4; ++r) acc[n][r] *= corr;
      }

      // exp2 + per-lane partial sum (cross-lane sum deferred to epilogue)
      float sc_[4];
#pragma unroll
      for (int c = 0; c < 4; ++c) {
#pragma unroll
        for (int r = 0; r < 4; ++r)
          st[c][r] = fast_exp2(st[c][r] - mrun);
        sc_[c] = (st[c][0] + st[c][1]) + (st[c][2] + st[c][3]);
      }
      lrun += (sc_[0] + sc_[1]) + (sc_[2] + sc_[3]);

      // pack P^T -> per-wave LDS (XOR-swizzled rows)
#pragma unroll
      for (int c = 0; c < 4; ++c) {
        uint2 ww;
        ww.x = pk_bf16(st[c][0], st[c][1]);
        ww.y = pk_bf16(st[c][2], st[c][3]);
        *(uint2*)(plb + ((l15 * 128 + c * 32 + g * 8) ^ swz)) = ww;
      }
      asm volatile("s_waitcnt lgkmcnt(0)" ::: "memory");
      __builtin_amdgcn_sched_barrier(0);
      short8 pf[2];
#pragma unroll
      for (int d2 = 0; d2 < 2; ++d2)
        pf[d2] = *(const short8*)(plb + ((l15 * 128 + d2 * 64 + g * 16) ^ swz));

      // PV: out^T[d][q], V fragments from LDS (swizzled)
      const unsigned short* Vc = VS[cur];
#pragma unroll
      for (int n = 0; n < 4; ++n) {
#pragma unroll
        for (int d2 = 0; d2 < 2; ++d2) {
          short8 vf = *(const short8*)(Vc + (n * 16 + l15) * 64 + (((d2 * 4 + g) ^ (l15 & 7)) * 8));
          acc[n] = __builtin_amdgcn_mfma_f32_16x16x32_bf16(vf, pf[d2], acc[n], 0, 0, 0);
        }
      }

      __syncthreads();   // drains vmcnt (stage done) + all waves done reading
      cur ^= 1;
    }

    // deferred cross-lane sum: once per half
    lrun += __shfl_xor(lrun, 16);
    lrun += __shfl_xor(lrun, 32);
    const float inv = 1.f / lrun;
    const size_t base = ((size_t)b * SSZ + qw0 + l15) * D_MODEL + h * DK;
#pragma unroll
    for (int n = 0; n < 4; ++n) {
      uint2 ww;
      ww.x = pk_bf16(acc[n][0] * inv, acc[n][1] * inv);
      ww.y = pk_bf16(acc[n][2] * inv, acc[n][3] * inv);
      *(uint2*)((char*)(Ob + base + n * 16 + g * 4)) = ww;
    }
    __syncthreads();   // buffers free before next half's prologue stage
  }
}

// ---------------------------------------------------------------- launch
extern "C" void kernel_launch(void* const* d_in, const int* in_sizes, int n_in,
                              void* d_out, int out_size, void* d_ws, size_t ws_size,
                              hipStream_t stream) {
  const float* x  = (const float*)d_in[0];
  const int* pos  = (const int*)d_in[1];
  const float* Qw = (const float*)d_in[2];
  const float* Kw = (const float*)d_in[3];
  const float* Vw = (const float*)d_in[4];
  const float* Ow = (const float*)d_in[5];
  float* out = (float*)d_out;

  unsigned short* xb   = (unsigned short*)d_ws;              // 8192*1024
  unsigned short* wqkv = xb + (size_t)M_TOT * D_MODEL;       // 3072*1024
  unsigned short* owb  = wqkv + (size_t)3 * D_MODEL * D_MODEL;
  unsigned short* Qb   = owb + (size_t)D_MODEL * D_MODEL;    // [64][2048][64]
  unsigned short* Kb   = Qb + (size_t)64 * SSZ * DK;
  unsigned short* Vt   = Kb + (size_t)64 * SSZ * DK;         // [64][64][2048]
  unsigned short* Ob   = Vt + (size_t)64 * SSZ * DK;         // [8192][1024]

  // 1. convert inputs to bf16
  {
    int total = M_TOT * D_MODEL + 4 * D_MODEL * D_MODEL;     // 12582912
    convert_kernel<<<total / 4 / 256, 256, 0, stream>>>(x, Qw, Kw, Vw, Ow, xb, wqkv, owb);
  }
  // 2. QKV projection (N=3072)
  gemm_kernel<0><<<dim3(M_TOT / 128, 3072 / 128), 256, 0, stream>>>(xb, wqkv, Qb, Kb, Vt, nullptr);
  // 3. RoPE in place on Q,K (Q gets 0.125*log2e folded in)
  rope_kernel<<<(64 * SSZ * 32) / 256, 256, 0, stream>>>(Qb, Kb, pos);
  // 4. causal flash attention (block-cooperative LDS staging, XCD-swizzled)
  attn_kernel<<<512, 512, 0, stream>>>(Qb, Kb, Vt, Ob);
  // 5. output projection -> fp32 d_out
  gemm_kernel<1><<<dim3(M_TOT / 128, D_MODEL / 128), 256, 0, stream>>>(Ob, owb, nullptr, nullptr, nullptr, out);
}